// Round 3
// baseline (705.994 us; speedup 1.0000x reference)
//
#include <hip/hip_runtime.h>
#include <math.h>

#define BB   64
#define SS   4096
#define ENC  512
#define DEC  512
#define NSPLIT 32
#define CHUNK (SS / NSPLIT)   // 128 rows per chunk, 32 rows per wave

// ---------------------------------------------------------------------------
// Kernel 1: sub[b,e] = sum_d dec[b,d] * W[e,d]     (F.linear: dec @ W^T)
// grid (4, B), block 256 (4 waves). Each wave computes 32 outputs e.
// ---------------------------------------------------------------------------
__global__ __launch_bounds__(256) void k_sub(const float* __restrict__ dec,
                                             const float* __restrict__ W,
                                             float* __restrict__ sub) {
    const int b    = blockIdx.y;
    const int lane = threadIdx.x & 63;
    const int wave = threadIdx.x >> 6;

    const float4* dv = (const float4*)(dec + (size_t)b * DEC);
    float4 q0 = dv[lane];
    float4 q1 = dv[lane + 64];

    const int e0 = blockIdx.x * 128 + wave * 32;
    for (int i = 0; i < 32; ++i) {
        const int e = e0 + i;
        const float4* wv = (const float4*)(W + (size_t)e * DEC);
        float4 w0 = wv[lane];
        float4 w1 = wv[lane + 64];
        float p = q0.x * w0.x + q0.y * w0.y + q0.z * w0.z + q0.w * w0.w
                + q1.x * w1.x + q1.y * w1.y + q1.z * w1.z + q1.w * w1.w;
        #pragma unroll
        for (int off = 32; off >= 1; off >>= 1) p += __shfl_xor(p, off, 64);
        if (lane == 0) sub[(size_t)b * ENC + e] = p;
    }
}

// ---------------------------------------------------------------------------
// Kernel 2: fused scores + online softmax + weighted accumulation.
// grid (NSPLIT, B), block 256 (4 waves). Each wave owns a contiguous 32-row
// strip and runs FOUR independent online-softmax chains (4 consecutive rows
// per iteration): 8 dwordx4 loads in flight per iter, 4 interleaved shuffle-
// reduce chains per butterfly level, one packed float4 attn_raw store.
// Chains merge pairwise at the end, then the 4 waves combine via LDS.
// ---------------------------------------------------------------------------
__global__ __launch_bounds__(256) void k_attn(const float* __restrict__ enc,
                                              const float* __restrict__ sub,
                                              float* __restrict__ attn_raw,
                                              float* __restrict__ chunk_m,
                                              float* __restrict__ chunk_l,
                                              float* __restrict__ chunk_acc) {
    const int b    = blockIdx.y;
    const int c    = blockIdx.x;
    const int lane = threadIdx.x & 63;
    const int wave = threadIdx.x >> 6;

    const float4* qv = (const float4*)(sub + (size_t)b * ENC);
    float4 q0 = qv[lane];          // dims [4*lane .. 4*lane+3]
    float4 q1 = qv[lane + 64];     // dims [256+4*lane .. 256+4*lane+3]

    float  m[4], l[4];
    float4 A0[4], A1[4];
    #pragma unroll
    for (int k = 0; k < 4; ++k) {
        m[k] = -INFINITY; l[k] = 0.f;
        A0[k] = make_float4(0.f, 0.f, 0.f, 0.f);
        A1[k] = make_float4(0.f, 0.f, 0.f, 0.f);
    }

    const int s0 = c * CHUNK + wave * 32;
    #pragma unroll 2
    for (int it = 0; it < 8; ++it) {
        const int r = s0 + it * 4;

        float4 e0[4], e1[4];
        #pragma unroll
        for (int k = 0; k < 4; ++k) {
            const float4* ev = (const float4*)(enc + ((size_t)b * SS + (r + k)) * ENC);
            e0[k] = ev[lane];
            e1[k] = ev[lane + 64];
        }

        float p[4];
        #pragma unroll
        for (int k = 0; k < 4; ++k) {
            p[k] = q0.x * e0[k].x + q0.y * e0[k].y + q0.z * e0[k].z + q0.w * e0[k].w
                 + q1.x * e1[k].x + q1.y * e1[k].y + q1.z * e1[k].z + q1.w * e1[k].w;
        }
        #pragma unroll
        for (int off = 32; off >= 1; off >>= 1) {
            #pragma unroll
            for (int k = 0; k < 4; ++k) p[k] += __shfl_xor(p[k], off, 64);
        }

        if (lane == 0) {
            *(float4*)(attn_raw + (size_t)b * SS + r) = make_float4(p[0], p[1], p[2], p[3]);
        }

        #pragma unroll
        for (int k = 0; k < 4; ++k) {
            const float mn = fmaxf(m[k], p[k]);
            const float al = __expf(m[k] - mn);   // exp(-inf)=0 handles first iter
            const float w  = __expf(p[k] - mn);
            l[k] = l[k] * al + w;
            A0[k].x = A0[k].x * al + w * e0[k].x;  A0[k].y = A0[k].y * al + w * e0[k].y;
            A0[k].z = A0[k].z * al + w * e0[k].z;  A0[k].w = A0[k].w * al + w * e0[k].w;
            A1[k].x = A1[k].x * al + w * e1[k].x;  A1[k].y = A1[k].y * al + w * e1[k].y;
            A1[k].z = A1[k].z * al + w * e1[k].z;  A1[k].w = A1[k].w * al + w * e1[k].w;
            m[k] = mn;
        }
    }

    // ---- merge the 4 chains of this wave ----
    const float mW = fmaxf(fmaxf(m[0], m[1]), fmaxf(m[2], m[3]));
    float f[4];
    #pragma unroll
    for (int k = 0; k < 4; ++k) f[k] = __expf(m[k] - mW);
    const float lw = l[0] * f[0] + l[1] * f[1] + l[2] * f[2] + l[3] * f[3];
    float4 a0, a1;
    a0.x = A0[0].x * f[0] + A0[1].x * f[1] + A0[2].x * f[2] + A0[3].x * f[3];
    a0.y = A0[0].y * f[0] + A0[1].y * f[1] + A0[2].y * f[2] + A0[3].y * f[3];
    a0.z = A0[0].z * f[0] + A0[1].z * f[1] + A0[2].z * f[2] + A0[3].z * f[3];
    a0.w = A0[0].w * f[0] + A0[1].w * f[1] + A0[2].w * f[2] + A0[3].w * f[3];
    a1.x = A1[0].x * f[0] + A1[1].x * f[1] + A1[2].x * f[2] + A1[3].x * f[3];
    a1.y = A1[0].y * f[0] + A1[1].y * f[1] + A1[2].y * f[2] + A1[3].y * f[3];
    a1.z = A1[0].z * f[0] + A1[1].z * f[1] + A1[2].z * f[2] + A1[3].z * f[3];
    a1.w = A1[0].w * f[0] + A1[1].w * f[1] + A1[2].w * f[2] + A1[3].w * f[3];

    // ---- combine the 4 waves of this block ----
    __shared__ float sm[4];
    __shared__ float sl[4];
    __shared__ float sacc[4][ENC];

    if (lane == 0) sm[wave] = mW;
    __syncthreads();
    const float M = fmaxf(fmaxf(sm[0], sm[1]), fmaxf(sm[2], sm[3]));
    const float g = __expf(mW - M);           // wave-uniform
    if (lane == 0) sl[wave] = lw * g;
    float* sa = &sacc[wave][0];
    sa[4 * lane + 0]       = a0.x * g;  sa[4 * lane + 1]       = a0.y * g;
    sa[4 * lane + 2]       = a0.z * g;  sa[4 * lane + 3]       = a0.w * g;
    sa[256 + 4 * lane + 0] = a1.x * g;  sa[256 + 4 * lane + 1] = a1.y * g;
    sa[256 + 4 * lane + 2] = a1.z * g;  sa[256 + 4 * lane + 3] = a1.w * g;
    __syncthreads();

    const size_t idx = (size_t)b * NSPLIT + c;
    if (threadIdx.x == 0) {
        chunk_m[idx] = M;
        chunk_l[idx] = sl[0] + sl[1] + sl[2] + sl[3];
    }
    for (int e = threadIdx.x; e < ENC; e += 256) {
        chunk_acc[idx * ENC + e] = sacc[0][e] + sacc[1][e] + sacc[2][e] + sacc[3][e];
    }
}

// ---------------------------------------------------------------------------
// Kernel 3: combine chunks -> sumResult; normalize attn in place.
// grid (B, NSPLIT), block 256. y==0 also produces sumResult.
// ---------------------------------------------------------------------------
__global__ __launch_bounds__(256) void k_final(const float* __restrict__ chunk_m,
                                               const float* __restrict__ chunk_l,
                                               const float* __restrict__ chunk_acc,
                                               float* __restrict__ attn,
                                               float* __restrict__ sumResult) {
    const int b = blockIdx.x;
    const int y = blockIdx.y;

    float M = -INFINITY;
    #pragma unroll
    for (int c = 0; c < NSPLIT; ++c) M = fmaxf(M, chunk_m[(size_t)b * NSPLIT + c]);
    float L = 0.f;
    #pragma unroll
    for (int c = 0; c < NSPLIT; ++c)
        L += chunk_l[(size_t)b * NSPLIT + c] * __expf(chunk_m[(size_t)b * NSPLIT + c] - M);
    const float invL = 1.f / L;

    if (y == 0) {
        float f[NSPLIT];
        #pragma unroll
        for (int c = 0; c < NSPLIT; ++c)
            f[c] = __expf(chunk_m[(size_t)b * NSPLIT + c] - M);
        for (int e = threadIdx.x; e < ENC; e += 256) {
            float s = 0.f;
            #pragma unroll
            for (int c = 0; c < NSPLIT; ++c)
                s += chunk_acc[((size_t)b * NSPLIT + c) * ENC + e] * f[c];
            sumResult[(size_t)b * ENC + e] = s * invL;
        }
    }

    const int s0 = y * (SS / NSPLIT);   // 128-wide slice
    for (int s = s0 + threadIdx.x; s < s0 + SS / NSPLIT; s += 256) {
        const size_t i = (size_t)b * SS + s;
        attn[i] = __expf(attn[i] - M) * invL;
    }
}

// ---------------------------------------------------------------------------
extern "C" void kernel_launch(void* const* d_in, const int* in_sizes, int n_in,
                              void* d_out, int out_size, void* d_ws, size_t ws_size,
                              hipStream_t stream) {
    const float* dec = (const float*)d_in[0];   // [B,1,DEC]
    const float* enc = (const float*)d_in[1];   // [B,S,ENC]
    const float* W   = (const float*)d_in[2];   // [ENC,DEC]

    float* out       = (float*)d_out;
    float* attn      = out;                               // B*S
    float* sumResult = out + (size_t)BB * SS;             // B*ENC

    float* ws        = (float*)d_ws;
    float* sub       = ws;                                // B*ENC
    float* chunk_m   = sub + (size_t)BB * ENC;            // B*NSPLIT
    float* chunk_l   = chunk_m + (size_t)BB * NSPLIT;     // B*NSPLIT
    float* chunk_acc = chunk_l + (size_t)BB * NSPLIT;     // B*NSPLIT*ENC

    k_sub  <<<dim3(4, BB),       256, 0, stream>>>(dec, W, sub);
    k_attn <<<dim3(NSPLIT, BB),  256, 0, stream>>>(enc, sub, attn, chunk_m, chunk_l, chunk_acc);
    k_final<<<dim3(BB, NSPLIT),  256, 0, stream>>>(chunk_m, chunk_l, chunk_acc, attn, sumResult);
}